// Round 3
// baseline (1328.154 us; speedup 1.0000x reference)
//
#include <hip/hip_runtime.h>
#include <cmath>

typedef __attribute__((ext_vector_type(8))) short short8;
typedef __attribute__((ext_vector_type(4))) float f32x4;
typedef unsigned short u16;

#define NB   16
#define NC   128
#define NS   64
#define NW   64
#define NHH  128
#define GSTR (NHH * NC * 3)

// workspace layout (bytes)
#define WI_OFF 0u            // Wi packed: 512*256*2 = 262144
#define WS_OFF 262144u       // Ws packed: 512*384*2 = 393216
#define FS_OFF 1048576u      // fs (bias included): 1024 * 512*64 * 2 = 67108864
#define WS_NEEDED (FS_OFF + (size_t)NB * NS * 512 * NW * 2)

__device__ __forceinline__ u16 f2bf(float f) {
    unsigned u = __builtin_bit_cast(unsigned, f);
    u += 0x7fffu + ((u >> 16) & 1u);
    return (u16)(u >> 16);
}
__device__ __forceinline__ float bfreg(uint2 u, int r) {
    unsigned w = (r < 2) ? u.x : u.y;
    unsigned bits = (r & 1) ? (w & 0xffff0000u) : (w << 16);
    return __builtin_bit_cast(float, bits);
}
__device__ __forceinline__ float fsig(float x) {
    return __builtin_amdgcn_rcpf(1.f + __builtin_amdgcn_exp2f(x * -1.442695041f));
}
__device__ __forceinline__ float ftanh(float x) {
    return 1.f - 2.f * __builtin_amdgcn_rcpf(1.f + __builtin_amdgcn_exp2f(x * 2.885390082f));
}

// ---------------- phase 0: pack weights into MFMA A-fragment layout (bf16) ----
__global__ void pack_weights(const float* __restrict__ w_itos,
                             const float* __restrict__ w_stos,
                             u16* __restrict__ wip, u16* __restrict__ wsp) {
    int e = blockIdx.x * 256 + threadIdx.x;
    if (e < 131072) {
        int j = e & 7, l = (e >> 3) & 63, kt = (e >> 9) & 7, wvg = e >> 12;
        int wv = wvg >> 2, g = wvg & 3;
        int m = 128 * g + 16 * wv + (l & 15);
        int k = kt * 32 + (l >> 4) * 8 + j;
        int dy = k >> 7, c = k & 127;
        wip[e] = f2bf(w_itos[(m * 128 + c) * 3 + dy]);   // dy in {0,1}; row 2 masked off
    } else if (e < 327680) {
        int e2 = e - 131072;
        int wvg = e2 / 6144, rem = e2 % 6144;
        int wv = wvg >> 2, g = wvg & 3;
        int kt = rem >> 9, l = (rem >> 3) & 63, j = rem & 7;
        int m = 128 * g + 16 * wv + (l & 15);
        int k = kt * 32 + (l >> 4) * 8 + j;
        int d = k >> 7, c = k & 127;
        wsp[e2] = f2bf(w_stos[(m * 128 + c) * 3 + d]);
    }
}

// ---------------- phase 1: input-to-state conv as bf16 MFMA GEMM --------------
// One block per (b,s). fs INCLUDES b_itos+b_stos. Layout:
// fsp[(bs*8+wv)*1024 + (g*4+n)*64 + l], packed bf16 pairs for acc rows r=0..3.
__global__ __launch_bounds__(512, 2) void itos_gemm(
    const float* __restrict__ image, const u16* __restrict__ wip,
    const float* __restrict__ b_itos, const float* __restrict__ b_stos,
    uint2* __restrict__ fsp) {
    const int bs = blockIdx.x, b = bs >> 6, s = bs & 63;
    const int t = threadIdx.x, wv = t >> 6, l = t & 63, lr = l & 15, lk = l >> 4;
    __shared__ u16 ImgT[64 * 256];   // [w][k], k = dy*128+c, XOR-swizzled

    {   // stage rows s-1 (dy=0) and s (dy=1), fp32 -> bf16, transposed
        const int r = t >> 1, half = t & 1;   // r = dy*128 + c
        const int dy = r >> 7, c = r & 127;
        const int s0 = s - 1 + dy;
        float v[32];
        if (s0 >= 0) {
            const float* src = image + (((size_t)b * NC + c) * NS + s0) * NW + half * 32;
            #pragma unroll
            for (int q = 0; q < 8; ++q) {
                float4 f = *(const float4*)(src + 4 * q);
                v[4*q] = f.x; v[4*q+1] = f.y; v[4*q+2] = f.z; v[4*q+3] = f.w;
            }
        } else {
            #pragma unroll
            for (int q = 0; q < 32; ++q) v[q] = 0.f;
        }
        #pragma unroll
        for (int q = 0; q < 32; ++q) {
            int w = half * 32 + q;
            ImgT[w * 256 + (r ^ ((w & 7) << 3))] = f2bf(v[q]);
        }
    }
    __syncthreads();

    f32x4 acc[4][4];
    #pragma unroll
    for (int g = 0; g < 4; ++g)
        #pragma unroll
        for (int n = 0; n < 4; ++n) acc[g][n] = (f32x4){0.f, 0.f, 0.f, 0.f};

    #pragma unroll
    for (int kt = 0; kt < 8; ++kt) {
        short8 a[4], bb[4];
        #pragma unroll
        for (int g = 0; g < 4; ++g)
            a[g] = *(const short8*)(wip + (((wv * 4 + g) * 8 + kt) * 64 + l) * 8);
        const int cu = kt * 32 + lk * 8;
        #pragma unroll
        for (int n = 0; n < 4; ++n) {
            const int w = n * 16 + lr;
            bb[n] = *(const short8*)&ImgT[w * 256 + (cu ^ ((w & 7) << 3))];
        }
        #pragma unroll
        for (int g = 0; g < 4; ++g)
            #pragma unroll
            for (int n = 0; n < 4; ++n)
                acc[g][n] = __builtin_amdgcn_mfma_f32_16x16x32_bf16(a[g], bb[n], acc[g][n], 0, 0, 0);
    }

    // fold both biases in (fp32, before bf16 rounding)
    float bias[4][4];
    #pragma unroll
    for (int g = 0; g < 4; ++g)
        #pragma unroll
        for (int r = 0; r < 4; ++r) {
            int m = 128 * g + 16 * wv + lk * 4 + r;
            bias[g][r] = b_itos[m] + b_stos[m];
        }

    uint2* dst = fsp + ((size_t)bs * 8 + wv) * 1024 + l;
    #pragma unroll
    for (int g = 0; g < 4; ++g)
        #pragma unroll
        for (int n = 0; n < 4; ++n) {
            uint2 u;
            u.x = (unsigned)f2bf(acc[g][n][0] + bias[g][0]) | ((unsigned)f2bf(acc[g][n][1] + bias[g][1]) << 16);
            u.y = (unsigned)f2bf(acc[g][n][2] + bias[g][2]) | ((unsigned)f2bf(acc[g][n][3] + bias[g][3]) << 16);
            dst[(g * 4 + n) * 64] = u;
        }
}

// ---------------- phase 2: recurrent state-to-state, one block per batch ------
// 16 waves: v = (vn<<3)|vh. Wave (vh,vn): gates 0..3, nh in [16vh,16vh+16),
// w in [32vn, 32vn+32). Ht double-buffered (32KB toggle), XOR-swizzled.
__global__ __launch_bounds__(1024) void rowlstm_rec16(
    const u16* __restrict__ wsp, const uint2* __restrict__ fsp,
    const float* __restrict__ h0, const float* __restrict__ c0,
    float* __restrict__ out) {
    const int b = blockIdx.x;
    const int t = threadIdx.x, v = t >> 6, l = t & 63, lr = l & 15, lk = l >> 4;
    const int vh = v & 7, vn = v >> 3;
    __shared__ u16 Ht[2 * 16384];   // two buffers at u16 offsets 0 / 16384

    // zero the 4 halo rows (wh=0,65 in both buffers)
    if (t < 512) {
        int i = t & 127, q = t >> 7;
        Ht[(q >> 1) * 16384 + ((q & 1) ? 65 : 0) * 128 + i] = 0;
    }
    // init h0 into buffer 0
    #pragma unroll
    for (int j = 0; j < 8; ++j) {
        int e = t * 8 + j, nh = e >> 6, w = e & 63, wh = w + 1;
        Ht[wh * 128 + (nh ^ ((wh & 7) << 3))] = f2bf(h0[e]);
    }

    float c_r[8];
    #pragma unroll
    for (int nn = 0; nn < 2; ++nn)
        #pragma unroll
        for (int r = 0; r < 4; ++r)
            c_r[nn * 4 + r] = c0[(16 * vh + lk * 4 + r) * 64 + (16 * (2 * vn + nn) + lr)];

    // incremental out pointers, one per r (nn via +16-elem imm offset)
    float* op[4];
    #pragma unroll
    for (int r = 0; r < 4; ++r)
        op[r] = out + ((size_t)b * NHH + (16 * vh + lk * 4 + r)) * (NS * NW)
                    + (16 * (2 * vn) + lr);

    const u16* wbase = wsp + vh * 24576;                       // vh slice: 4g*12kt*64l*8
    const uint2* fsb = fsp + ((size_t)b * 64 * 8 + vh) * 1024 + l;

    __syncthreads();

    uint2 fsv[4][2];
    #pragma unroll
    for (int g = 0; g < 4; ++g)
        #pragma unroll
        for (int nn = 0; nn < 2; ++nn)
            fsv[g][nn] = fsb[(g * 4 + 2 * vn + nn) * 64];

    unsigned cur = 0;
    for (int s = 0; s < NS; ++s) {
        // accumulator starts at fs (bias already folded in)
        f32x4 acc[4][2];
        #pragma unroll
        for (int g = 0; g < 4; ++g)
            #pragma unroll
            for (int nn = 0; nn < 2; ++nn)
                #pragma unroll
                for (int r = 0; r < 4; ++r)
                    acc[g][nn][r] = bfreg(fsv[g][nn], r);

        #pragma unroll
        for (int kt = 0; kt < 12; ++kt) {
            const int d = kt >> 2, kc = kt & 3;
            short8 a[4], bb[2];
            #pragma unroll
            for (int g = 0; g < 4; ++g)
                a[g] = *(const short8*)(wbase + ((g * 12 + kt) * 64 + l) * 8);
            const int cu = kc * 32 + lk * 8;
            #pragma unroll
            for (int nn = 0; nn < 2; ++nn) {
                const int wh = (2 * vn + nn) * 16 + lr + d;   // h index = wh-1 = w+d-1
                bb[nn] = *(const short8*)&Ht[cur + wh * 128 + (cu ^ ((wh & 7) << 3))];
            }
            #pragma unroll
            for (int g = 0; g < 4; ++g)
                #pragma unroll
                for (int nn = 0; nn < 2; ++nn)
                    acc[g][nn] = __builtin_amdgcn_mfma_f32_16x16x32_bf16(a[g], bb[nn], acc[g][nn], 0, 0, 0);
        }

        // gating epilogue (8 elems/lane); h_new = c_OLD * sigmoid(o)
        uint2 hw[2];
        #pragma unroll
        for (int nn = 0; nn < 2; ++nn) {
            u16 hb[4];
            #pragma unroll
            for (int r = 0; r < 4; ++r) {
                const float si = fsig(acc[0][nn][r]);
                const float tg = ftanh(acc[1][nn][r]);
                const float sf = fsig(acc[2][nn][r]);
                const float so = fsig(acc[3][nn][r]);
                const float cold = c_r[nn * 4 + r];
                c_r[nn * 4 + r] = sf * cold + si * tg;
                const float hn = cold * so;
                *(op[r] + nn * 16) = hn;
                hb[r] = f2bf(hn);
            }
            hw[nn].x = (unsigned)hb[0] | ((unsigned)hb[1] << 16);
            hw[nn].y = (unsigned)hb[2] | ((unsigned)hb[3] << 16);
        }
        #pragma unroll
        for (int r = 0; r < 4; ++r) op[r] += NW;

        // prefetch fs for next step (stays in flight across the barrier)
        if (s < NS - 1) {
            #pragma unroll
            for (int g = 0; g < 4; ++g)
                #pragma unroll
                for (int nn = 0; nn < 2; ++nn)
                    fsv[g][nn] = fsb[(size_t)(s + 1) * 8192 + (g * 4 + 2 * vn + nn) * 64];
        }

        // write h_new into the OTHER buffer (packed 4 bf16 per ds_write_b64)
        const unsigned nxt = cur ^ 16384;
        #pragma unroll
        for (int nn = 0; nn < 2; ++nn) {
            const int nh0 = 16 * vh + lk * 4;
            const int wh = 16 * (2 * vn + nn) + lr + 1;
            *(uint2*)&Ht[nxt + wh * 128 + (nh0 ^ ((wh & 7) << 3))] = hw[nn];
        }

        // single barrier per step: drain LDS only, vmem stays in flight
        asm volatile("s_waitcnt lgkmcnt(0)" ::: "memory");
        __builtin_amdgcn_s_barrier();
        asm volatile("" ::: "memory");
        cur = nxt;
    }
}

// ---------------- fallback (validated round-1 fp32 kernel) --------------------
__global__ __launch_bounds__(512, 2) void rowlstm_f32(
    const float* __restrict__ image, const float* __restrict__ w_itos,
    const float* __restrict__ b_itos, const float* __restrict__ w_stos,
    const float* __restrict__ b_stos, const float* __restrict__ h0,
    const float* __restrict__ c0, float* __restrict__ out) {
    const int b = blockIdx.x, t = threadIdx.x, wq = t & 3, nh = t >> 2, w0 = wq * 16;
    __shared__ float h_lds[NHH][NW + 2];
    #pragma unroll
    for (int j = 0; j < 16; ++j) h_lds[nh][1 + w0 + j] = h0[nh * NW + w0 + j];
    if (wq == 0) { h_lds[nh][0] = 0.f; h_lds[nh][NW + 1] = 0.f; }
    float c_r[16];
    #pragma unroll
    for (int j = 0; j < 16; ++j) c_r[j] = c0[nh * NW + w0 + j];
    const float bias[4] = {
        b_itos[0 * NHH + nh] + b_stos[0 * NHH + nh], b_itos[1 * NHH + nh] + b_stos[1 * NHH + nh],
        b_itos[2 * NHH + nh] + b_stos[2 * NHH + nh], b_itos[3 * NHH + nh] + b_stos[3 * NHH + nh]};
    const float* img_b = image + (size_t)b * NC * NS * NW;
    __syncthreads();
    for (int s = 0; s < NS; ++s) {
        float acc[4][16];
        #pragma unroll
        for (int g = 0; g < 4; ++g)
            #pragma unroll
            for (int j = 0; j < 16; ++j) acc[g][j] = bias[g];
        #pragma unroll 2
        for (int ci = 0; ci < NC; ++ci) {
            float imp[16], imc[16];
            const float* iprow = img_b + ((size_t)ci * NS + s) * NW + w0;
            #pragma unroll
            for (int q = 0; q < 4; ++q) {
                float4 vv = *(const float4*)(iprow + 4 * q);
                imc[4*q] = vv.x; imc[4*q+1] = vv.y; imc[4*q+2] = vv.z; imc[4*q+3] = vv.w;
            }
            if (s > 0) {
                #pragma unroll
                for (int q = 0; q < 4; ++q) {
                    float4 vv = *(const float4*)(iprow - NW + 4 * q);
                    imp[4*q] = vv.x; imp[4*q+1] = vv.y; imp[4*q+2] = vv.z; imp[4*q+3] = vv.w;
                }
            } else {
                #pragma unroll
                for (int j = 0; j < 16; ++j) imp[j] = 0.f;
            }
            float hv[18];
            #pragma unroll
            for (int j = 0; j < 18; ++j) hv[j] = h_lds[ci][w0 + j];
            const float* wip2 = w_itos + ((size_t)nh * NC + ci) * 3;
            const float* wsp2 = w_stos + ((size_t)nh * NHH + ci) * 3;
            #pragma unroll
            for (int g = 0; g < 4; ++g) {
                const float wi0 = wip2[(size_t)g * GSTR + 0], wi1 = wip2[(size_t)g * GSTR + 1];
                const float ws0 = wsp2[(size_t)g * GSTR + 0], ws1 = wsp2[(size_t)g * GSTR + 1],
                            ws2 = wsp2[(size_t)g * GSTR + 2];
                #pragma unroll
                for (int j = 0; j < 16; ++j)
                    acc[g][j] += wi0 * imp[j] + wi1 * imc[j] + ws0 * hv[j] + ws1 * hv[j+1] + ws2 * hv[j+2];
            }
        }
        float hn[16];
        #pragma unroll
        for (int j = 0; j < 16; ++j) {
            const float si = 1.f / (1.f + __expf(-acc[0][j]));
            const float tg = tanhf(acc[1][j]);
            const float sf = 1.f / (1.f + __expf(-acc[2][j]));
            const float so = 1.f / (1.f + __expf(-acc[3][j]));
            const float cold = c_r[j];
            c_r[j] = sf * cold + si * tg;
            hn[j] = cold * so;
        }
        __syncthreads();
        #pragma unroll
        for (int j = 0; j < 16; ++j) h_lds[nh][1 + w0 + j] = hn[j];
        float* opp = out + (((size_t)b * NHH + nh) * NS + s) * NW + w0;
        #pragma unroll
        for (int q = 0; q < 4; ++q)
            *(float4*)(opp + 4 * q) = make_float4(hn[4*q], hn[4*q+1], hn[4*q+2], hn[4*q+3]);
        __syncthreads();
    }
}

extern "C" void kernel_launch(void* const* d_in, const int* in_sizes, int n_in,
                              void* d_out, int out_size, void* d_ws, size_t ws_size,
                              hipStream_t stream) {
    const float* image  = (const float*)d_in[0];
    const float* w_itos = (const float*)d_in[1];
    const float* b_itos = (const float*)d_in[2];
    const float* w_stos = (const float*)d_in[3];
    const float* b_stos = (const float*)d_in[4];
    const float* h0     = (const float*)d_in[5];
    const float* c0     = (const float*)d_in[6];
    float* out = (float*)d_out;

    if (ws_size >= WS_NEEDED) {
        u16*  wip = (u16*)((char*)d_ws + WI_OFF);
        u16*  wsp = (u16*)((char*)d_ws + WS_OFF);
        uint2* fsp = (uint2*)((char*)d_ws + FS_OFF);
        pack_weights<<<1280, 256, 0, stream>>>(w_itos, w_stos, wip, wsp);
        itos_gemm<<<1024, 512, 0, stream>>>(image, wip, b_itos, b_stos, fsp);
        rowlstm_rec16<<<NB, 1024, 0, stream>>>(wsp, fsp, h0, c0, out);
    } else {
        rowlstm_f32<<<NB, 512, 0, stream>>>(image, w_itos, b_itos, w_stos, b_stos, h0, c0, out);
    }
}

// Round 4
// 728.341 us; speedup vs baseline: 1.8235x; 1.8235x over previous
//
#include <hip/hip_runtime.h>
#include <cmath>

typedef __attribute__((ext_vector_type(8))) short short8;
typedef __attribute__((ext_vector_type(4))) float f32x4;
typedef _Float16 h4 __attribute__((ext_vector_type(4)));
typedef _Float16 h8 __attribute__((ext_vector_type(8)));
typedef unsigned short u16;

#define NB   16
#define NC   128
#define NS   64
#define NW   64
#define NHH  128
#define GSTR (NHH * NC * 3)

// workspace layout (bytes)
#define WI_OFF 0u            // Wi packed: 512*256*2 = 262144
#define WS_OFF 262144u       // Ws packed: 512*384*2 = 393216
#define FS_OFF 1048576u      // fs (bias included): 1024 * 512*64 * 2 = 67108864
#define WS_NEEDED (FS_OFF + (size_t)NB * NS * 512 * NW * 2)

__device__ __forceinline__ u16 f2bf(float f) {
    unsigned u = __builtin_bit_cast(unsigned, f);
    u += 0x7fffu + ((u >> 16) & 1u);
    return (u16)(u >> 16);
}
__device__ __forceinline__ float bfreg(uint2 u, int r) {
    unsigned w = (r < 2) ? u.x : u.y;
    unsigned bits = (r & 1) ? (w & 0xffff0000u) : (w << 16);
    return __builtin_bit_cast(float, bits);
}
__device__ __forceinline__ float fsig(float x) {
    return __builtin_amdgcn_rcpf(1.f + __builtin_amdgcn_exp2f(x * -1.442695041f));
}
__device__ __forceinline__ float ftanh(float x) {
    return 1.f - 2.f * __builtin_amdgcn_rcpf(1.f + __builtin_amdgcn_exp2f(x * 2.885390082f));
}

// ---------------- phase 0: pack weights into MFMA A-fragment layout (bf16) ----
// Wi layout (consumed by itos_gemm, unchanged from validated R2/R3):
//   wip[(((wv*4+g)*8+kt)*64+l)*8+j], m=128g+16wv+(l&15), k=kt*32+(l>>4)*8+j -> (dy,c)
// Ws layout (gate-split, consumed by rowlstm_gs):
//   wsp[((((g*4+q)*12+kt)*2+mi)*64+l)*8+j], m=128g+32q+16mi+(l&15), k -> (d,c)
__global__ void pack_weights(const float* __restrict__ w_itos,
                             const float* __restrict__ w_stos,
                             u16* __restrict__ wip, u16* __restrict__ wsp) {
    int e = blockIdx.x * 256 + threadIdx.x;
    if (e < 131072) {
        int j = e & 7, l = (e >> 3) & 63, kt = (e >> 9) & 7, wvg = e >> 12;
        int wv = wvg >> 2, g = wvg & 3;
        int m = 128 * g + 16 * wv + (l & 15);
        int k = kt * 32 + (l >> 4) * 8 + j;
        int dy = k >> 7, c = k & 127;
        wip[e] = f2bf(w_itos[(m * 128 + c) * 3 + dy]);   // dy in {0,1}; row 2 masked off
    } else if (e < 327680) {
        int e2 = e - 131072;
        int j = e2 & 7;
        int tmp = e2 >> 3;          // ((gq*12+kt)*2+mi)*64 + l
        int l = tmp & 63;
        int tmp2 = tmp >> 6;        // (gq*12+kt)*2+mi
        int mi = tmp2 & 1;
        int tmp3 = tmp2 >> 1;       // gq*12+kt
        int kt = tmp3 % 12, gq = tmp3 / 12;
        int g = gq >> 2, q = gq & 3;
        int m = 128 * g + 32 * q + 16 * mi + (l & 15);
        int k = kt * 32 + (l >> 4) * 8 + j;
        int d = k >> 7, c = k & 127;
        wsp[e2] = f2bf(w_stos[(m * 128 + c) * 3 + d]);
    }
}

// ---------------- phase 1: input-to-state conv as bf16 MFMA GEMM --------------
// One block per (b,s). fs INCLUDES b_itos+b_stos. Layout:
// fsp[(bs*8+wv)*1024 + (g*4+n)*64 + l], packed bf16 pairs for acc rows r=0..3.
__global__ __launch_bounds__(512, 2) void itos_gemm(
    const float* __restrict__ image, const u16* __restrict__ wip,
    const float* __restrict__ b_itos, const float* __restrict__ b_stos,
    uint2* __restrict__ fsp) {
    const int bs = blockIdx.x, b = bs >> 6, s = bs & 63;
    const int t = threadIdx.x, wv = t >> 6, l = t & 63, lr = l & 15, lk = l >> 4;
    __shared__ u16 ImgT[64 * 256];   // [w][k], k = dy*128+c, XOR-swizzled

    {   // stage rows s-1 (dy=0) and s (dy=1), fp32 -> bf16, transposed
        const int r = t >> 1, half = t & 1;   // r = dy*128 + c
        const int dy = r >> 7, c = r & 127;
        const int s0 = s - 1 + dy;
        float v[32];
        if (s0 >= 0) {
            const float* src = image + (((size_t)b * NC + c) * NS + s0) * NW + half * 32;
            #pragma unroll
            for (int qq = 0; qq < 8; ++qq) {
                float4 f = *(const float4*)(src + 4 * qq);
                v[4*qq] = f.x; v[4*qq+1] = f.y; v[4*qq+2] = f.z; v[4*qq+3] = f.w;
            }
        } else {
            #pragma unroll
            for (int qq = 0; qq < 32; ++qq) v[qq] = 0.f;
        }
        #pragma unroll
        for (int qq = 0; qq < 32; ++qq) {
            int w = half * 32 + qq;
            ImgT[w * 256 + (r ^ ((w & 7) << 3))] = f2bf(v[qq]);
        }
    }
    __syncthreads();

    f32x4 acc[4][4];
    #pragma unroll
    for (int g = 0; g < 4; ++g)
        #pragma unroll
        for (int n = 0; n < 4; ++n) acc[g][n] = (f32x4){0.f, 0.f, 0.f, 0.f};

    #pragma unroll
    for (int kt = 0; kt < 8; ++kt) {
        short8 a[4], bb[4];
        #pragma unroll
        for (int g = 0; g < 4; ++g)
            a[g] = *(const short8*)(wip + (((wv * 4 + g) * 8 + kt) * 64 + l) * 8);
        const int cu = kt * 32 + lk * 8;
        #pragma unroll
        for (int n = 0; n < 4; ++n) {
            const int w = n * 16 + lr;
            bb[n] = *(const short8*)&ImgT[w * 256 + (cu ^ ((w & 7) << 3))];
        }
        #pragma unroll
        for (int g = 0; g < 4; ++g)
            #pragma unroll
            for (int n = 0; n < 4; ++n)
                acc[g][n] = __builtin_amdgcn_mfma_f32_16x16x32_bf16(a[g], bb[n], acc[g][n], 0, 0, 0);
    }

    // fold both biases in (fp32, before bf16 rounding)
    float bias[4][4];
    #pragma unroll
    for (int g = 0; g < 4; ++g)
        #pragma unroll
        for (int r = 0; r < 4; ++r) {
            int m = 128 * g + 16 * wv + lk * 4 + r;
            bias[g][r] = b_itos[m] + b_stos[m];
        }

    uint2* dst = fsp + ((size_t)bs * 8 + wv) * 1024 + l;
    #pragma unroll
    for (int g = 0; g < 4; ++g)
        #pragma unroll
        for (int n = 0; n < 4; ++n) {
            uint2 u;
            u.x = (unsigned)f2bf(acc[g][n][0] + bias[g][0]) | ((unsigned)f2bf(acc[g][n][1] + bias[g][1]) << 16);
            u.y = (unsigned)f2bf(acc[g][n][2] + bias[g][2]) | ((unsigned)f2bf(acc[g][n][3] + bias[g][3]) << 16);
            dst[(g * 4 + n) * 64] = u;
        }
}

// ---------------- phase 2: recurrent, gate-split, one block per batch ---------
// 16 waves: v = g*4 + q. Wave (g,q): gate g, nh in [32q,32q+32) (mi=0,1), all w.
// Preacts exchanged through f16 LDS plane; epilogue threads own (nhB=8*(t>>6), w=t&63).
__global__ __launch_bounds__(1024, 4) void rowlstm_gs(
    const u16* __restrict__ wsp, const uint2* __restrict__ fsp,
    const float* __restrict__ h0, const float* __restrict__ c0,
    float* __restrict__ out) {
    const int b = blockIdx.x;
    const int t = threadIdx.x, v = t >> 6, l = t & 63, lr = l & 15, lk = l >> 4;
    const int g = v >> 2, q = v & 3;

    __shared__ u16 lds[16896 + 32768];   // Ht double buffer (2*66*128) + preact (4*64*128)
    u16* Ht  = lds;
    u16* pre = lds + 16896;

    // zero the 4 halo rows (wh=0,65 in both Ht buffers)
    if (t < 512) {
        int i = t & 127, z = t >> 7;
        Ht[(z >> 1) * 8448 + ((z & 1) ? 65 : 0) * 128 + i] = 0;
    }
    // h0 into buffer 0
    #pragma unroll
    for (int j = 0; j < 8; ++j) {
        int e = t * 8 + j, nh = e >> 6, w = e & 63, wh = w + 1;
        Ht[wh * 128 + (nh ^ ((wh & 7) << 3))] = f2bf(h0[e]);
    }

    // epilogue ownership
    const int wE = t & 63, nhB = (t >> 6) * 8;
    float c_r[8];
    #pragma unroll
    for (int i = 0; i < 8; ++i) c_r[i] = c0[(nhB + i) * 64 + wE];
    float* outp = out + ((size_t)b * NHH + nhB) * (NS * NW) + wE;

    // GEMM bases
    const u16* wbase = wsp + (g * 4 + q) * 12288;            // 12kt*2mi*64l*8
    const uint2* fsb0 = fsp + ((size_t)b * 512 + (2 * q + 0)) * 1024 + (g * 4) * 64 + l;
    const uint2* fsb1 = fsp + ((size_t)b * 512 + (2 * q + 1)) * 1024 + (g * 4) * 64 + l;

    __syncthreads();

    uint2 fsv[2][4];
    #pragma unroll
    for (int n = 0; n < 4; ++n) { fsv[0][n] = fsb0[n * 64]; fsv[1][n] = fsb1[n * 64]; }

    unsigned cur = 0;
    for (int s = 0; s < NS; ++s) {
        // ---- phase A: GEMM (this wave's gate, 32 nh rows, 64 w cols) ----
        f32x4 acc[2][4];
        #pragma unroll
        for (int mi = 0; mi < 2; ++mi)
            #pragma unroll
            for (int n = 0; n < 4; ++n)
                #pragma unroll
                for (int r = 0; r < 4; ++r)
                    acc[mi][n][r] = bfreg(fsv[mi][n], r);

        // prefetch fs for next step (in flight across both barriers)
        if (s < NS - 1) {
            #pragma unroll
            for (int n = 0; n < 4; ++n) {
                fsv[0][n] = fsb0[(size_t)(s + 1) * 8192 + n * 64];
                fsv[1][n] = fsb1[(size_t)(s + 1) * 8192 + n * 64];
            }
        }

        #pragma unroll
        for (int kt = 0; kt < 12; ++kt) {
            const int d = kt >> 2, kc = kt & 3;
            short8 a0 = *(const short8*)(wbase + ((kt * 2 + 0) * 64 + l) * 8);
            short8 a1 = *(const short8*)(wbase + ((kt * 2 + 1) * 64 + l) * 8);
            const int cu = kc * 32 + lk * 8;
            short8 bb[4];
            #pragma unroll
            for (int n = 0; n < 4; ++n) {
                const int wh = n * 16 + lr + d;   // h index = wh-1 = w+d-1
                bb[n] = *(const short8*)&Ht[cur + wh * 128 + (cu ^ ((wh & 7) << 3))];
            }
            #pragma unroll
            for (int n = 0; n < 4; ++n) {
                acc[0][n] = __builtin_amdgcn_mfma_f32_16x16x32_bf16(a0, bb[n], acc[0][n], 0, 0, 0);
                acc[1][n] = __builtin_amdgcn_mfma_f32_16x16x32_bf16(a1, bb[n], acc[1][n], 0, 0, 0);
            }
        }

        // write preacts (f16) to the exchange plane
        #pragma unroll
        for (int mi = 0; mi < 2; ++mi)
            #pragma unroll
            for (int n = 0; n < 4; ++n) {
                const int w = n * 16 + lr;
                const int m0 = 32 * q + 16 * mi + lk * 4;
                h4 ph;
                #pragma unroll
                for (int r = 0; r < 4; ++r) ph[r] = (_Float16)acc[mi][n][r];
                *(h4*)&pre[(g * 64 + w) * 128 + (m0 ^ ((w & 15) << 3))] = ph;
            }

        asm volatile("s_waitcnt lgkmcnt(0)" ::: "memory");
        __builtin_amdgcn_s_barrier();
        asm volatile("" ::: "memory");

        // ---- phase B: epilogue, 8 nh per thread ----
        h8 P[4];
        #pragma unroll
        for (int gg = 0; gg < 4; ++gg)
            P[gg] = *(const h8*)&pre[(gg * 64 + wE) * 128 + (nhB ^ ((wE & 15) << 3))];

        short8 hv8;
        #pragma unroll
        for (int i = 0; i < 8; ++i) {
            const float si = fsig((float)P[0][i]);
            const float tg = ftanh((float)P[1][i]);
            const float sf = fsig((float)P[2][i]);
            const float so = fsig((float)P[3][i]);
            const float cold = c_r[i];
            c_r[i] = sf * cold + si * tg;
            const float hn = cold * so;          // previous cell state, per reference
            outp[(size_t)i * (NS * NW)] = hn;
            hv8[i] = (short)f2bf(hn);
        }

        const unsigned nxt = cur ^ 8448;
        const int whE = wE + 1;
        *(short8*)&Ht[nxt + whE * 128 + (nhB ^ ((whE & 7) << 3))] = hv8;

        asm volatile("s_waitcnt lgkmcnt(0)" ::: "memory");
        __builtin_amdgcn_s_barrier();
        asm volatile("" ::: "memory");
        cur = nxt;
        outp += NW;
    }
}

// ---------------- fallback (validated round-1 fp32 kernel) --------------------
__global__ __launch_bounds__(512, 2) void rowlstm_f32(
    const float* __restrict__ image, const float* __restrict__ w_itos,
    const float* __restrict__ b_itos, const float* __restrict__ w_stos,
    const float* __restrict__ b_stos, const float* __restrict__ h0,
    const float* __restrict__ c0, float* __restrict__ out) {
    const int b = blockIdx.x, t = threadIdx.x, wq = t & 3, nh = t >> 2, w0 = wq * 16;
    __shared__ float h_lds[NHH][NW + 2];
    #pragma unroll
    for (int j = 0; j < 16; ++j) h_lds[nh][1 + w0 + j] = h0[nh * NW + w0 + j];
    if (wq == 0) { h_lds[nh][0] = 0.f; h_lds[nh][NW + 1] = 0.f; }
    float c_r[16];
    #pragma unroll
    for (int j = 0; j < 16; ++j) c_r[j] = c0[nh * NW + w0 + j];
    const float bias[4] = {
        b_itos[0 * NHH + nh] + b_stos[0 * NHH + nh], b_itos[1 * NHH + nh] + b_stos[1 * NHH + nh],
        b_itos[2 * NHH + nh] + b_stos[2 * NHH + nh], b_itos[3 * NHH + nh] + b_stos[3 * NHH + nh]};
    const float* img_b = image + (size_t)b * NC * NS * NW;
    __syncthreads();
    for (int s = 0; s < NS; ++s) {
        float acc[4][16];
        #pragma unroll
        for (int g = 0; g < 4; ++g)
            #pragma unroll
            for (int j = 0; j < 16; ++j) acc[g][j] = bias[g];
        #pragma unroll 2
        for (int ci = 0; ci < NC; ++ci) {
            float imp[16], imc[16];
            const float* iprow = img_b + ((size_t)ci * NS + s) * NW + w0;
            #pragma unroll
            for (int qq = 0; qq < 4; ++qq) {
                float4 vv = *(const float4*)(iprow + 4 * qq);
                imc[4*qq] = vv.x; imc[4*qq+1] = vv.y; imc[4*qq+2] = vv.z; imc[4*qq+3] = vv.w;
            }
            if (s > 0) {
                #pragma unroll
                for (int qq = 0; qq < 4; ++qq) {
                    float4 vv = *(const float4*)(iprow - NW + 4 * qq);
                    imp[4*qq] = vv.x; imp[4*qq+1] = vv.y; imp[4*qq+2] = vv.z; imp[4*qq+3] = vv.w;
                }
            } else {
                #pragma unroll
                for (int j = 0; j < 16; ++j) imp[j] = 0.f;
            }
            float hv[18];
            #pragma unroll
            for (int j = 0; j < 18; ++j) hv[j] = h_lds[ci][w0 + j];
            const float* wip2 = w_itos + ((size_t)nh * NC + ci) * 3;
            const float* wsp2 = w_stos + ((size_t)nh * NHH + ci) * 3;
            #pragma unroll
            for (int g = 0; g < 4; ++g) {
                const float wi0 = wip2[(size_t)g * GSTR + 0], wi1 = wip2[(size_t)g * GSTR + 1];
                const float ws0 = wsp2[(size_t)g * GSTR + 0], ws1 = wsp2[(size_t)g * GSTR + 1],
                            ws2 = wsp2[(size_t)g * GSTR + 2];
                #pragma unroll
                for (int j = 0; j < 16; ++j)
                    acc[g][j] += wi0 * imp[j] + wi1 * imc[j] + ws0 * hv[j] + ws1 * hv[j+1] + ws2 * hv[j+2];
            }
        }
        float hn[16];
        #pragma unroll
        for (int j = 0; j < 16; ++j) {
            const float si = 1.f / (1.f + __expf(-acc[0][j]));
            const float tg = tanhf(acc[1][j]);
            const float sf = 1.f / (1.f + __expf(-acc[2][j]));
            const float so = 1.f / (1.f + __expf(-acc[3][j]));
            const float cold = c_r[j];
            c_r[j] = sf * cold + si * tg;
            hn[j] = cold * so;
        }
        __syncthreads();
        #pragma unroll
        for (int j = 0; j < 16; ++j) h_lds[nh][1 + w0 + j] = hn[j];
        float* opp = out + (((size_t)b * NHH + nh) * NS + s) * NW + w0;
        #pragma unroll
        for (int qq = 0; qq < 4; ++qq)
            *(float4*)(opp + 4 * qq) = make_float4(hn[4*qq], hn[4*qq+1], hn[4*qq+2], hn[4*qq+3]);
        __syncthreads();
    }
}

extern "C" void kernel_launch(void* const* d_in, const int* in_sizes, int n_in,
                              void* d_out, int out_size, void* d_ws, size_t ws_size,
                              hipStream_t stream) {
    const float* image  = (const float*)d_in[0];
    const float* w_itos = (const float*)d_in[1];
    const float* b_itos = (const float*)d_in[2];
    const float* w_stos = (const float*)d_in[3];
    const float* b_stos = (const float*)d_in[4];
    const float* h0     = (const float*)d_in[5];
    const float* c0     = (const float*)d_in[6];
    float* out = (float*)d_out;

    if (ws_size >= WS_NEEDED) {
        u16*  wip = (u16*)((char*)d_ws + WI_OFF);
        u16*  wsp = (u16*)((char*)d_ws + WS_OFF);
        uint2* fsp = (uint2*)((char*)d_ws + FS_OFF);
        pack_weights<<<1280, 256, 0, stream>>>(w_itos, w_stos, wip, wsp);
        itos_gemm<<<1024, 512, 0, stream>>>(image, wip, b_itos, b_stos, fsp);
        rowlstm_gs<<<NB, 1024, 0, stream>>>(wsp, fsp, h0, c0, out);
    } else {
        rowlstm_f32<<<NB, 512, 0, stream>>>(image, w_itos, b_itos, w_stos, b_stos, h0, c0, out);
    }
}